// Round 8
// baseline (116.279 us; speedup 1.0000x reference)
//
#include <hip/hip_runtime.h>

#define NQ 32768
#define NC 8192
#define CFEAT 128
#define CSPLIT 64
#define TILE (NC / CSPLIT)   // 128 coords per split
#define BLK 256
#define QPT 4                // queries per thread
#define QPB (BLK * QPT)      // 1024 queries per block

// ws layout: [0, 8 MB) f32 bestd[CSPLIT][NQ]; then float4 ctab[NC] (128 KB).
// bestd is [split][query] so phase-1 stores are lane-coalesced (256 B/wave);
// the [query][split] layout in R7 scattered 4 B stores across 64 lines/wave
// -> ~128 MB partial-line writeback at the kernel-boundary flush.
#define BESTD_OFF 0
#define CTAB_OFF ((size_t)CSPLIT * NQ * 4)

// Precompute coord table (-2cx,-2cy,-2cz,cc) once.
// cc rounding order matches np.sum(coords*coords, -1): ((x*x+y*y)+z*z).
__global__ __launch_bounds__(256) void init_ctab(
    const float* __restrict__ coords, float4* __restrict__ ctab) {
  const int t = blockIdx.x * 256 + threadIdx.x;   // grid covers NC threads
  const float cx = coords[t * 3 + 0];
  const float cy = coords[t * 3 + 1];
  const float cz = coords[t * 3 + 2];
  const float cc = __fadd_rn(
      __fadd_rn(__fmul_rn(cx, cx), __fmul_rn(cy, cy)), __fmul_rn(cz, cz));
  ctab[t] = make_float4(-2.0f * cx, -2.0f * cy, -2.0f * cz, cc);
}

// Phase 1: per-split min DISTANCE only — no index tracking, no atomics.
// 5 VALU/pair (mul,fma,fma,add,min) -> 17 us floor. ctab reads are
// wave-uniform -> compiler scalarizes to batched s_load (SGPR=80 confirms).
//
// Numerics (BIT-EXACT vs harness reference, verified absmax=0.0):
//   t = (-2cx)*px; t = fma(-2cy,py,t); t = fma(-2cz,pz,t); d = cc + t
// (-2 pre-fold is a power-of-2 scale: exact, commutes with round-to-nearest.)
// min value is order-independent (inputs finite) -> bit-exact min.
__global__ __launch_bounds__(BLK, 8) void argmin_split(
    const float4* __restrict__ ctab, const float* __restrict__ points,
    float* __restrict__ bestd) {
  const int s = blockIdx.y;
  const int base = s * TILE;
  const int q0 = blockIdx.x * QPB + threadIdx.x;

  float px[QPT], py[QPT], pz[QPT], best[QPT];
  #pragma unroll
  for (int k = 0; k < QPT; ++k) {
    const int q = q0 + k * BLK;
    px[k] = points[q * 3 + 0];
    py[k] = points[q * 3 + 1];
    pz[k] = points[q * 3 + 2];
    best[k] = __builtin_inff();
  }

  #pragma unroll 8
  for (int i = 0; i < TILE; ++i) {
    const float4 c = ctab[base + i];     // wave-uniform -> s_load into SGPRs
    #pragma unroll
    for (int k = 0; k < QPT; ++k) {
      float t = __fmul_rn(c.x, px[k]);
      t = __fmaf_rn(c.y, py[k], t);
      t = __fmaf_rn(c.z, pz[k], t);
      const float d = __fadd_rn(c.w, t);
      best[k] = fminf(best[k], d);       // v_min_f32, 1 inst
    }
  }

  #pragma unroll
  for (int k = 0; k < QPT; ++k) {
    const int q = q0 + k * BLK;
    bestd[(size_t)s * NQ + q] = best[k]; // lane-coalesced 256 B/wave store
  }
}

// Phase 2 (one wave per query, fused): reduce 64 split-mins -> global min +
// lowest winning split (ballot/ffs = lowest lane on value ties); rescan that
// split's 128 coords (bit-exact recompute guarantees an equality hit; first
// match = lowest index). Tiebreak chain == np.argmin's global first-index.
// Then gather the 128-float feature row with 64 lanes x float2.
// bestd read is strided (lane l -> split l), but each 64 B line serves 16
// consecutive-q waves -> L2-absorbed.
__global__ __launch_bounds__(256) void rescan_gather(
    const float4* __restrict__ ctab, const float* __restrict__ points,
    const float* __restrict__ bestd, const float* __restrict__ feature,
    float2* __restrict__ out) {
  const int q = blockIdx.x * 4 + (threadIdx.x >> 6);
  const int l = threadIdx.x & 63;

  const float v = bestd[(size_t)l * NQ + q];    // split l's min for query q
  float m = v;
  #pragma unroll
  for (int off = 32; off; off >>= 1) m = fminf(m, __shfl_xor(m, off, 64));
  const unsigned long long bs = __ballot(v == m);
  const int sstar = __ffsll(bs) - 1;            // lowest split attaining min

  const float px = points[q * 3 + 0];           // wave-uniform
  const float py = points[q * 3 + 1];
  const float pz = points[q * 3 + 2];
  const int base = sstar * TILE;

  const float4 c0 = ctab[base + l];             // coalesced, lanes consecutive
  const float4 c1 = ctab[base + 64 + l];
  float t0 = __fmul_rn(c0.x, px);
  t0 = __fmaf_rn(c0.y, py, t0);
  t0 = __fmaf_rn(c0.z, pz, t0);
  const float d0 = __fadd_rn(c0.w, t0);
  float t1 = __fmul_rn(c1.x, px);
  t1 = __fmaf_rn(c1.y, py, t1);
  t1 = __fmaf_rn(c1.z, pz, t1);
  const float d1 = __fadd_rn(c1.w, t1);

  const unsigned long long b0 = __ballot(d0 == m);
  const unsigned long long b1 = __ballot(d1 == m);
  const int off_in = b0 ? (__ffsll(b0) - 1) : (64 + __ffsll(b1) - 1);
  const int idx = base + off_in;

  const float2* fr = (const float2*)(feature + (size_t)idx * CFEAT);
  out[(size_t)q * (CFEAT / 2) + l] = fr[l];
}

extern "C" void kernel_launch(void* const* d_in, const int* in_sizes, int n_in,
                              void* d_out, int out_size, void* d_ws, size_t ws_size,
                              hipStream_t stream) {
  const float* coords  = (const float*)d_in[0];   // [8192, 3]
  const float* feature = (const float*)d_in[1];   // [8192, 128]
  const float* points  = (const float*)d_in[2];   // [32768, 3]
  float* out = (float*)d_out;                     // [32768, 128]

  float* bestd = (float*)((char*)d_ws + BESTD_OFF);
  float4* ctab = (float4*)((char*)d_ws + CTAB_OFF);

  init_ctab<<<NC / 256, 256, 0, stream>>>(coords, ctab);

  dim3 grid1(NQ / QPB, CSPLIT);                   // (32, 64) = 2048 blocks
  argmin_split<<<grid1, BLK, 0, stream>>>(ctab, points, bestd);

  rescan_gather<<<NQ / 4, 256, 0, stream>>>(ctab, points, bestd, feature,
                                            (float2*)out);
}